// Round 1
// 1242.849 us; speedup vs baseline: 1.0153x; 1.0153x over previous
//
#include <hip/hip_runtime.h>
#include <stdint.h>

typedef unsigned short u16;
typedef __attribute__((ext_vector_type(8))) __bf16 bf16x8;
typedef __attribute__((ext_vector_type(4))) float f32x4;

#define TTS 256
#define NSEG 1024
#define TC 32            // time-chunk for gates

__device__ __forceinline__ u16 f2bf(float f) {
  union { float f; uint32_t u; } v; v.f = f;
  uint32_t r = v.u + 0x7fffu + ((v.u >> 16) & 1u);
  return (u16)(r >> 16);
}
__device__ __forceinline__ float bf2f(u16 h) {
  union { uint32_t u; float f; } v; v.u = ((uint32_t)h) << 16;
  return v.f;
}
__device__ __forceinline__ float sigm(float x) {
  return __builtin_amdgcn_rcpf(1.0f + __expf(-x));
}
// async global->LDS, 16B per lane; LDS dest must be wave-uniform base + lane*16
__device__ __forceinline__ void gl16(const void* g, void* l) {
  __builtin_amdgcn_global_load_lds(
      (const __attribute__((address_space(1))) unsigned int*)g,
      (__attribute__((address_space(3))) unsigned int*)l, 16, 0, 0);
}

// ---------------- K0: transpose small weight, fp32 -> bf16 ----------------
__global__ void k_transp(const float* __restrict__ in, u16* __restrict__ out, int R, int C) {
  int i = blockIdx.x * blockDim.x + threadIdx.x;
  if (i < R * C) {
    int r = i / C, c = i % C;
    out[(size_t)c * R + r] = f2bf(in[i]);
  }
}

// ---------------- K1/K3c: bf16 MFMA GEMM, 128x256 tile, BK=32, 512 thr ----------------
// AMODE 0: A fp32 row-major [M][K] (K1: x), convert in-register, ds_write staging.
// AMODE 1: A bf16 chunked x_att [seg][k>>6][t][64], rows m = seg*TC + tt, t = t0+tt;
//          staged via global_load_lds (16B/lane, LDS linear in tid).
// B always staged via global_load_lds.
// STORE_T: write chunked convT layout [seg][f>>6][f&63][t]. Else row-major [M][Nld].
template <bool RELU, bool STORE_T, int AMODE>
__global__ __launch_bounds__(512, 4) void k_gemm(
    const void* __restrict__ Av, const u16* __restrict__ Bt,
    const float* __restrict__ bias, u16* __restrict__ out, int K, int Nld, int t0) {
  __shared__ __attribute__((aligned(16))) u16 ldsA[4096];   // [c 4][row 128][8]
  __shared__ __attribute__((aligned(16))) u16 ldsB[8192];   // [c 4][row 256][8]
  const int tid  = threadIdx.x;
  const int w    = tid >> 6;
  const int lane = tid & 63;
  const int quad = lane >> 4;
  const int l16  = lane & 15;
  const int m0 = blockIdx.x * 128;
  const int n0 = blockIdx.y * 256;
  const int wm = w >> 2, wn = w & 3;          // 2x4 wave grid, wave tile 64x64
  const int arow = tid & 127, ac = tid >> 7;  // A staging: (k-subchunk, row)

  f32x4 acc[4][4];
#pragma unroll
  for (int i = 0; i < 4; i++)
#pragma unroll
    for (int j = 0; j < 4; j++) acc[i][j] = f32x4{0.f, 0.f, 0.f, 0.f};

  for (int k0 = 0; k0 < K; k0 += 32) {
    ushort4 va0, va1;
    if (AMODE == 0) {
      const float* Af = (const float*)Av;
      const float* p = Af + (size_t)(m0 + arow) * K + k0 + ac * 8;
      float4 f0 = *(const float4*)p;
      float4 f1 = *(const float4*)(p + 4);
      va0 = ushort4{f2bf(f0.x), f2bf(f0.y), f2bf(f0.z), f2bf(f0.w)};
      va1 = ushort4{f2bf(f1.x), f2bf(f1.y), f2bf(f1.z), f2bf(f1.w)};
    }
    __syncthreads();  // prior iteration's ds_reads complete before overwrite
    if (AMODE == 0) {
      *(ushort4*)&ldsA[tid * 8]     = va0;
      *(ushort4*)&ldsA[tid * 8 + 4] = va1;
    } else {
      const u16* Ax = (const u16*)Av;
      int r = m0 + arow;
      int kk = k0 + ac * 8;
      gl16(Ax + (size_t)(r >> 5) * 65536 + (size_t)(kk >> 6) * 16384 +
               (t0 + (r & 31)) * 64 + (kk & 63),
           &ldsA[tid * 8]);
    }
#pragma unroll
    for (int i = 0; i < 2; i++) {
      int idx = i * 512 + tid;
      int brow = idx & 255, bc = idx >> 8;
      gl16(Bt + (size_t)(n0 + brow) * K + k0 + bc * 8, &ldsB[idx * 8]);
    }
    __syncthreads();  // drains vmcnt (gl16 landed) + lgkmcnt (ds_writes)
    bf16x8 a[4], b[4];
#pragma unroll
    for (int i = 0; i < 4; i++)
      a[i] = *(const bf16x8*)&ldsA[(quad * 128 + wm * 64 + i * 16 + l16) * 8];
#pragma unroll
    for (int j = 0; j < 4; j++)
      b[j] = *(const bf16x8*)&ldsB[(quad * 256 + wn * 64 + j * 16 + l16) * 8];
#pragma unroll
    for (int i = 0; i < 4; i++)
#pragma unroll
      for (int j = 0; j < 4; j++)
        acc[i][j] = __builtin_amdgcn_mfma_f32_16x16x32_bf16(a[i], b[j], acc[i][j], 0, 0, 0);
  }

#pragma unroll
  for (int j = 0; j < 4; j++) {
    int col = n0 + wn * 64 + j * 16 + l16;
    float bv = bias[col];
#pragma unroll
    for (int i = 0; i < 4; i++) {
      int row0 = m0 + wm * 64 + i * 16 + quad * 4;  // 4 consecutive rows
      if (STORE_T) {
        int nseg = row0 >> 8, tt0 = row0 & 255;
        ushort4 o;
        float v0 = acc[i][j][0] + bv, v1 = acc[i][j][1] + bv;
        float v2 = acc[i][j][2] + bv, v3 = acc[i][j][3] + bv;
        if (RELU) {
          v0 = fmaxf(v0, 0.f); v1 = fmaxf(v1, 0.f);
          v2 = fmaxf(v2, 0.f); v3 = fmaxf(v3, 0.f);
        }
        o.x = f2bf(v0); o.y = f2bf(v1); o.z = f2bf(v2); o.w = f2bf(v3);
        *(ushort4*)&out[(size_t)nseg * 65536 + (size_t)(col >> 6) * 16384 +
                        (col & 63) * 256 + tt0] = o;
      } else {
#pragma unroll
        for (int r = 0; r < 4; r++) {
          float v = acc[i][j][r] + bv;
          if (RELU) v = fmaxf(v, 0.f);
          out[(size_t)(row0 + r) * Nld + col] = f2bf(v);
        }
      }
    }
  }
}

// ---------------- K2: attention (in-place on xac), plain-load staging ----------------
__global__ __launch_bounds__(256) void k_attn(
    u16* xac,
    const u16* __restrict__ Wt,       // attn_w^T: [t'][t] 256x256
    const float* __restrict__ attn_b) {
  __shared__ u16 ldsW[8192];          // per-stage Wt tile [c 4][t' 256][8]
  __shared__ u16 ldsC[16384];         // conv resident [tchunk 32][f 64][8]
  __shared__ float redmax[4][64];
  __shared__ float redsum[4][64];
  const int tid  = threadIdx.x;
  const int w    = tid >> 6;
  const int lane = tid & 63;
  const int quad = lane >> 4;
  const int l16  = lane & 15;
  const int seg = blockIdx.x;
  const int c4  = blockIdx.y;
  u16* reg = xac + (size_t)seg * 65536 + (size_t)c4 * 16384;

  {
    const int f = tid & 63, g = tid >> 6;
#pragma unroll
    for (int u = 0; u < 8; u++) {
      int tch = g * 8 + u;
      *(bf16x8*)&ldsC[(tch * 64 + f) * 8] =
          *(const bf16x8*)(reg + (size_t)f * 256 + tch * 8);
    }
  }

  f32x4 acc[4][4];
#pragma unroll
  for (int i = 0; i < 4; i++)
#pragma unroll
    for (int j = 0; j < 4; j++) acc[i][j] = f32x4{0.f, 0.f, 0.f, 0.f};

  for (int s = 0; s < 8; s++) {
    int k0 = s * 32;
    bf16x8 vw[4];
#pragma unroll
    for (int c = 0; c < 4; c++)
      vw[c] = *(const bf16x8*)(Wt + (size_t)tid * 256 + k0 + c * 8);
    __syncthreads();
#pragma unroll
    for (int c = 0; c < 4; c++)
      *(bf16x8*)&ldsW[(c * 256 + tid) * 8] = vw[c];
    __syncthreads();
    bf16x8 a[4], b[4];
#pragma unroll
    for (int i = 0; i < 4; i++)
      a[i] = *(const bf16x8*)&ldsW[(quad * 256 + w * 64 + i * 16 + l16) * 8];
#pragma unroll
    for (int j = 0; j < 4; j++)
      b[j] = *(const bf16x8*)&ldsC[((s * 4 + quad) * 64 + j * 16 + l16) * 8];
#pragma unroll
    for (int i = 0; i < 4; i++)
#pragma unroll
      for (int j = 0; j < 4; j++)
        acc[i][j] = __builtin_amdgcn_mfma_f32_16x16x32_bf16(a[i], b[j], acc[i][j], 0, 0, 0);
  }

#pragma unroll
  for (int i = 0; i < 4; i++)
#pragma unroll
    for (int r = 0; r < 4; r++) {
      float ab = attn_b[w * 64 + i * 16 + quad * 4 + r];
#pragma unroll
      for (int j = 0; j < 4; j++) acc[i][j][r] += ab;
    }

  float lmax[4];
#pragma unroll
  for (int j = 0; j < 4; j++) {
    float m = -1e30f;
#pragma unroll
    for (int i = 0; i < 4; i++)
#pragma unroll
      for (int r = 0; r < 4; r++) m = fmaxf(m, acc[i][j][r]);
    m = fmaxf(m, __shfl_xor(m, 16));
    m = fmaxf(m, __shfl_xor(m, 32));
    lmax[j] = m;
  }
  __syncthreads();
  if (quad == 0) {
#pragma unroll
    for (int j = 0; j < 4; j++) redmax[w][j * 16 + l16] = lmax[j];
  }
  __syncthreads();
  float gmax[4];
#pragma unroll
  for (int j = 0; j < 4; j++) {
    int c = j * 16 + l16;
    gmax[j] = fmaxf(fmaxf(redmax[0][c], redmax[1][c]), fmaxf(redmax[2][c], redmax[3][c]));
  }
  float lsum[4];
#pragma unroll
  for (int j = 0; j < 4; j++) {
    float sacc = 0.f;
#pragma unroll
    for (int i = 0; i < 4; i++)
#pragma unroll
      for (int r = 0; r < 4; r++) {
        float e = __expf(acc[i][j][r] - gmax[j]);
        acc[i][j][r] = e;
        sacc += e;
      }
    sacc += __shfl_xor(sacc, 16);
    sacc += __shfl_xor(sacc, 32);
    lsum[j] = sacc;
  }
  if (quad == 0) {
#pragma unroll
    for (int j = 0; j < 4; j++) redsum[w][j * 16 + l16] = lsum[j];
  }
  __syncthreads();
  float rinv[4];
#pragma unroll
  for (int j = 0; j < 4; j++) {
    int c = j * 16 + l16;
    rinv[j] = 1.0f / (redsum[0][c] + redsum[1][c] + redsum[2][c] + redsum[3][c]);
  }

#pragma unroll
  for (int i = 0; i < 4; i++) {
#pragma unroll
    for (int r = 0; r < 4; r++) {
      int tp = w * 64 + i * 16 + quad * 4 + r;
#pragma unroll
      for (int j = 0; j < 4; j++) {
        int fl = j * 16 + l16;
        float cv = bf2f(ldsC[((tp >> 3) * 64 + fl) * 8 + (tp & 7)]);
        float xa = acc[i][j][r] * rinv[j] * cv;
        reg[(size_t)tp * 64 + fl] = f2bf(xa);
      }
    }
  }
}

// ---------------- K4c: GRU scan over one time chunk (TC steps) ----------------
// 64 blocks x 512 thr (8 waves), 16 segs/block. Ut fragments: 4 of 6 sets
// register-resident (g0 z,r,h + g1 h = 128 VGPR), 2 sets (g1 z,r) staged in
// LDS once per launch. Per-step global traffic: gates only (h-independent).
// h carried between chunks via hio (= d_out) in fp32.
__global__ __launch_bounds__(512, 2) void k_scanc(
    const u16* __restrict__ gc,   // gates chunk [NSEG*TC][768] (x@W + bi)
    const u16* __restrict__ Ut,   // gru_u^T [768][256]
    const float* __restrict__ br, // gru_b[1]: [768]
    float* __restrict__ hio,      // [NSEG][256] fp32 (d_out)
    int init) {
  __shared__ u16 uls[65536];      // [w 8][set 2][s 8][lane 64][8]  = 128 KB
  __shared__ u16 hb[16 * 264];    // bf16 h, row stride 264
  const int tid  = threadIdx.x;
  const int w    = tid >> 6;
  const int lane = tid & 63;
  const int quad = lane >> 4;
  const int l16  = lane & 15;
  const int n0 = blockIdx.x * 16;
  const int cg[2] = {w, 8 + w};   // two col-groups per wave

  // stage g1 z,r Ut fragments into LDS (once)
#pragma unroll
  for (int j = 0; j < 2; j++)
#pragma unroll
    for (int s = 0; s < 8; s++)
      *(bf16x8*)&uls[w * 8192 + (j * 8 + s) * 512 + lane * 8] =
          *(const bf16x8*)(Ut + (size_t)(j * 256 + cg[1] * 16 + l16) * 256 + s * 32 + quad * 8);

  // register-resident Ut fragments: g0 all gates, g1 gate h
  bf16x8 ur0[3][8], urh1[8];
#pragma unroll
  for (int g = 0; g < 3; g++)
#pragma unroll
    for (int s = 0; s < 8; s++)
      ur0[g][s] = *(const bf16x8*)(Ut + (size_t)(g * 256 + cg[0] * 16 + l16) * 256 + s * 32 + quad * 8);
#pragma unroll
  for (int s = 0; s < 8; s++)
    urh1[s] = *(const bf16x8*)(Ut + (size_t)(512 + cg[1] * 16 + l16) * 256 + s * 32 + quad * 8);

  // biases per (group, gate)
  float brZ[2], brR[2], brH[2];
#pragma unroll
  for (int grp = 0; grp < 2; grp++) {
    int c = cg[grp] * 16 + l16;
    brZ[grp] = br[c]; brR[grp] = br[256 + c]; brH[grp] = br[512 + c];
  }

  // h init: registers (this lane's 4 segs x 2 groups) + hb for all 16 segs
  float hreg[2][4];
#pragma unroll
  for (int grp = 0; grp < 2; grp++)
#pragma unroll
    for (int r = 0; r < 4; r++)
      hreg[grp][r] = init ? 0.f
                          : hio[(size_t)(n0 + quad * 4 + r) * 256 + cg[grp] * 16 + l16];
  {
    int sg = tid >> 5, c0 = (tid & 31) * 8;   // 16 segs x 256 cols / 512 thr
    if (init) {
      *(ushort4*)&hb[sg * 264 + c0]     = ushort4{0, 0, 0, 0};
      *(ushort4*)&hb[sg * 264 + c0 + 4] = ushort4{0, 0, 0, 0};
    } else {
      const float* hp = hio + (size_t)(n0 + sg) * 256 + c0;
      float4 h0 = *(const float4*)(hp), h1 = *(const float4*)(hp + 4);
      *(ushort4*)&hb[sg * 264 + c0]     = ushort4{f2bf(h0.x), f2bf(h0.y), f2bf(h0.z), f2bf(h0.w)};
      *(ushort4*)&hb[sg * 264 + c0 + 4] = ushort4{f2bf(h1.x), f2bf(h1.y), f2bf(h1.z), f2bf(h1.w)};
    }
  }
  // gates row bases for this lane's 4 segs
  const u16* gseg[4];
#pragma unroll
  for (int r = 0; r < 4; r++)
    gseg[r] = gc + (size_t)(n0 + quad * 4 + r) * TC * 768;
  __syncthreads();

  for (int tt = 0; tt < TC; tt++) {
    // prefetch gates[tt] (h-independent)
    float gg[2][3][4];
#pragma unroll
    for (int grp = 0; grp < 2; grp++)
#pragma unroll
      for (int g = 0; g < 3; g++)
#pragma unroll
        for (int r = 0; r < 4; r++)
          gg[grp][g][r] = bf2f(gseg[r][tt * 768 + g * 256 + cg[grp] * 16 + l16]);

    f32x4 acc[2][3];
#pragma unroll
    for (int grp = 0; grp < 2; grp++)
#pragma unroll
      for (int g = 0; g < 3; g++) acc[grp][g] = f32x4{0.f, 0.f, 0.f, 0.f};

#pragma unroll
    for (int s = 0; s < 8; s++) {
      bf16x8 ah = *(const bf16x8*)&hb[l16 * 264 + s * 32 + quad * 8];
#pragma unroll
      for (int g = 0; g < 3; g++)
        acc[0][g] = __builtin_amdgcn_mfma_f32_16x16x32_bf16(ah, ur0[g][s], acc[0][g], 0, 0, 0);
      bf16x8 uz = *(const bf16x8*)&uls[w * 8192 + s * 512 + lane * 8];
      bf16x8 urr = *(const bf16x8*)&uls[w * 8192 + (8 + s) * 512 + lane * 8];
      acc[1][0] = __builtin_amdgcn_mfma_f32_16x16x32_bf16(ah, uz,      acc[1][0], 0, 0, 0);
      acc[1][1] = __builtin_amdgcn_mfma_f32_16x16x32_bf16(ah, urr,     acc[1][1], 0, 0, 0);
      acc[1][2] = __builtin_amdgcn_mfma_f32_16x16x32_bf16(ah, urh1[s], acc[1][2], 0, 0, 0);
    }
    __syncthreads();   // all hb reads complete before overwrite

#pragma unroll
    for (int grp = 0; grp < 2; grp++)
#pragma unroll
      for (int r = 0; r < 4; r++) {
        float z  = sigm(acc[grp][0][r] + gg[grp][0][r] + brZ[grp]);
        float rg = sigm(acc[grp][1][r] + gg[grp][1][r] + brR[grp]);
        float hh = fmaxf(gg[grp][2][r] + rg * (acc[grp][2][r] + brH[grp]), 0.f);
        float hn = z * hreg[grp][r] + (1.0f - z) * hh;
        hreg[grp][r] = hn;
        hb[(quad * 4 + r) * 264 + cg[grp] * 16 + l16] = f2bf(hn);
      }
    __syncthreads();   // writes visible before next step's reads
  }

#pragma unroll
  for (int grp = 0; grp < 2; grp++)
#pragma unroll
    for (int r = 0; r < 4; r++)
      hio[(size_t)(n0 + quad * 4 + r) * 256 + cg[grp] * 16 + l16] = hreg[grp][r];
}

// ---------------- host ----------------
extern "C" void kernel_launch(void* const* d_in, const int* in_sizes, int n_in,
                              void* d_out, int out_size, void* d_ws, size_t ws_size,
                              hipStream_t stream) {
  (void)in_sizes; (void)n_in; (void)out_size;
  const float* x      = (const float*)d_in[0];
  const float* conv_w = (const float*)d_in[1];
  const float* conv_b = (const float*)d_in[2];
  const float* attn_w = (const float*)d_in[3];
  const float* attn_b = (const float*)d_in[4];
  const float* gru_w  = (const float*)d_in[5];
  const float* gru_u  = (const float*)d_in[6];
  const float* gru_b  = (const float*)d_in[7];

  // scratch layout: 185,532,416 B total (known-safe: < 202,309,696 proven)
  const size_t NEEDED = 185532416;
  if (ws_size < NEEDED) return;
  char* ws = (char*)d_ws;
  u16* xac     = (u16*)(ws);                  // 134217728 B: convT then x_att (chunked, in-place)
  u16* gatesC  = (u16*)(ws + 134217728);      //  50331648 B: gates for one 32-step chunk
  u16* conv_wT = (u16*)(ws + 184549376);      //     65536 B [f][c]
  u16* attn_wT = (u16*)(ws + 184614912);      //    131072 B [t'][t]
  u16* gru_wT  = (u16*)(ws + 184745984);      //    393216 B [j][f]
  u16* gru_uT  = (u16*)(ws + 185139200);      //    393216 B [j][k]

  hipLaunchKernelGGL(k_transp, dim3(128), dim3(256), 0, stream, conv_w, conv_wT, 128, 256);
  hipLaunchKernelGGL(k_transp, dim3(256), dim3(256), 0, stream, attn_w, attn_wT, 256, 256);
  hipLaunchKernelGGL(k_transp, dim3(768), dim3(256), 0, stream, gru_w, gru_wT, 256, 768);
  hipLaunchKernelGGL(k_transp, dim3(768), dim3(256), 0, stream, gru_u, gru_uT, 256, 768);

  // K1: conv = relu(x @ conv_w + b); full N=256 per block -> fp32 A read ONCE
  hipLaunchKernelGGL((k_gemm<true, true, 0>), dim3(2048, 1), dim3(512), 0, stream,
                     (const void*)x, conv_wT, conv_b, xac, 128, 0, 0);
  // K2: attention softmax + multiply, in place on xac
  hipLaunchKernelGGL(k_attn, dim3(1024, 4), dim3(256), 0, stream,
                     xac, attn_wT, attn_b);
  // K3c/K4c: 8 time chunks of (gates GEMM -> 32-step scan); h lives in d_out
  // gates grid (256,3): 256 % 8 == 0 keeps all 3 n-passes of an m-tile on the
  // same XCD; A per XCD = 2 MB < 4 MB L2 -> A effectively fetched once.
  for (int c = 0; c < 8; c++) {
    hipLaunchKernelGGL((k_gemm<false, false, 1>), dim3(256, 3), dim3(512), 0, stream,
                       (const void*)xac, gru_wT, gru_b, gatesC, 256, 768, c * TC);
    hipLaunchKernelGGL(k_scanc, dim3(64), dim3(512), 0, stream,
                       gatesC, gru_uT, gru_b + 768, (float*)d_out, c == 0 ? 1 : 0);
  }
}

// Round 2
// 1239.353 us; speedup vs baseline: 1.0182x; 1.0028x over previous
//
#include <hip/hip_runtime.h>
#include <stdint.h>

typedef unsigned short u16;
typedef __attribute__((ext_vector_type(8))) __bf16 bf16x8;
typedef __attribute__((ext_vector_type(4))) float f32x4;

#define TTS 256
#define NSEG 1024
#define TC 32            // time-chunk for gates

__device__ __forceinline__ u16 f2bf(float f) {
  union { float f; uint32_t u; } v; v.f = f;
  uint32_t r = v.u + 0x7fffu + ((v.u >> 16) & 1u);
  return (u16)(r >> 16);
}
__device__ __forceinline__ float bf2f(u16 h) {
  union { uint32_t u; float f; } v; v.u = ((uint32_t)h) << 16;
  return v.f;
}
__device__ __forceinline__ float sigm(float x) {
  return __builtin_amdgcn_rcpf(1.0f + __expf(-x));
}
// async global->LDS, 16B per lane; LDS dest must be wave-uniform base + lane*16
__device__ __forceinline__ void gl16(const void* g, void* l) {
  __builtin_amdgcn_global_load_lds(
      (const __attribute__((address_space(1))) unsigned int*)g,
      (__attribute__((address_space(3))) unsigned int*)l, 16, 0, 0);
}

// ---------------- K0: transpose small weight, fp32 -> bf16 ----------------
__global__ void k_transp(const float* __restrict__ in, u16* __restrict__ out, int R, int C) {
  int i = blockIdx.x * blockDim.x + threadIdx.x;
  if (i < R * C) {
    int r = i / C, c = i % C;
    out[(size_t)c * R + r] = f2bf(in[i]);
  }
}

// ---------------- K1/K3c: bf16 MFMA GEMM, 128x256 tile, BK=32, 512 thr ----------------
// 2-phase double-buffered: stage tile k+1 (global_load_lds / reg-split for fp32)
// while MFMA'ing tile k; ONE barrier per K-step. launch_bounds (512,2) so the
// compiler is NOT forced below the ~130 VGPR this kernel needs (no spills).
// AMODE 0: A fp32 row-major [M][K] (K1: x), load->convert->ds_write staging.
// AMODE 1: A bf16 chunked x_att [seg][k>>6][t][64], staged via global_load_lds.
// STORE_T: write chunked convT layout [seg][f>>6][f&63][t]. Else row-major [M][Nld].
template <bool RELU, bool STORE_T, int AMODE>
__global__ __launch_bounds__(512, 2) void k_gemm(
    const void* __restrict__ Av, const u16* __restrict__ Bt,
    const float* __restrict__ bias, u16* __restrict__ out, int K, int Nld, int t0) {
  __shared__ __attribute__((aligned(16))) u16 ldsA[2][4096];   // [c 4][row 128][8]
  __shared__ __attribute__((aligned(16))) u16 ldsB[2][8192];   // [c 4][row 256][8]
  const int tid  = threadIdx.x;
  const int w    = tid >> 6;
  const int lane = tid & 63;
  const int quad = lane >> 4;
  const int l16  = lane & 15;
  const int m0 = blockIdx.x * 128;
  const int n0 = blockIdx.y * 256;
  const int wm = w >> 2, wn = w & 3;          // 2x4 wave grid, wave tile 64x64
  const int arow = tid & 127, ac = tid >> 7;  // A staging: (row, k-subchunk)
  const float* Af = (const float*)Av;
  const u16*   Ax = (const u16*)Av;

  f32x4 acc[4][4];
#pragma unroll
  for (int i = 0; i < 4; i++)
#pragma unroll
    for (int j = 0; j < 4; j++) acc[i][j] = f32x4{0.f, 0.f, 0.f, 0.f};

  // ---- prologue: stage k0=0 into buffer 0 ----
  float4 p0, p1;
  if (AMODE == 0) {
    const float* p = Af + (size_t)(m0 + arow) * K + ac * 8;
    p0 = *(const float4*)p;
    p1 = *(const float4*)(p + 4);
  } else {
    int r = m0 + arow, kk = ac * 8;
    gl16(Ax + (size_t)(r >> 5) * 65536 + (size_t)(kk >> 6) * 16384 +
             (t0 + (r & 31)) * 64 + (kk & 63),
         &ldsA[0][tid * 8]);
  }
#pragma unroll
  for (int i = 0; i < 2; i++) {
    int idx = i * 512 + tid, brow = idx & 255, bc = idx >> 8;
    gl16(Bt + (size_t)(n0 + brow) * K + bc * 8, &ldsB[0][idx * 8]);
  }
  if (AMODE == 0) {
    *(ushort4*)&ldsA[0][tid * 8]     = ushort4{f2bf(p0.x), f2bf(p0.y), f2bf(p0.z), f2bf(p0.w)};
    *(ushort4*)&ldsA[0][tid * 8 + 4] = ushort4{f2bf(p1.x), f2bf(p1.y), f2bf(p1.z), f2bf(p1.w)};
  }
  __syncthreads();   // vmcnt drained (gl16 landed) + ds_writes visible

  int cur = 0;
  for (int k0 = 0; k0 < K; k0 += 32) {
    const int kn = k0 + 32;
    const bool more = kn < K;
    // ---- issue next-tile staging into buf cur^1 (before compute) ----
    float4 q0, q1;
    if (more) {
      if (AMODE == 0) {
        const float* p = Af + (size_t)(m0 + arow) * K + kn + ac * 8;
        q0 = *(const float4*)p;
        q1 = *(const float4*)(p + 4);
      } else {
        int r = m0 + arow, kk = kn + ac * 8;
        gl16(Ax + (size_t)(r >> 5) * 65536 + (size_t)(kk >> 6) * 16384 +
                 (t0 + (r & 31)) * 64 + (kk & 63),
             &ldsA[cur ^ 1][tid * 8]);
      }
#pragma unroll
      for (int i = 0; i < 2; i++) {
        int idx = i * 512 + tid, brow = idx & 255, bc = idx >> 8;
        gl16(Bt + (size_t)(n0 + brow) * K + kn + bc * 8, &ldsB[cur ^ 1][idx * 8]);
      }
    }
    // ---- compute on buf cur ----
    bf16x8 a[4], b[4];
#pragma unroll
    for (int i = 0; i < 4; i++)
      a[i] = *(const bf16x8*)&ldsA[cur][(quad * 128 + wm * 64 + i * 16 + l16) * 8];
#pragma unroll
    for (int j = 0; j < 4; j++)
      b[j] = *(const bf16x8*)&ldsB[cur][(quad * 256 + wn * 64 + j * 16 + l16) * 8];
#pragma unroll
    for (int i = 0; i < 4; i++)
#pragma unroll
      for (int j = 0; j < 4; j++)
        acc[i][j] = __builtin_amdgcn_mfma_f32_16x16x32_bf16(a[i], b[j], acc[i][j], 0, 0, 0);
    // fp32-A path: convert+write next tile after compute (loads have landed by now)
    if (AMODE == 0 && more) {
      *(ushort4*)&ldsA[cur ^ 1][tid * 8]     = ushort4{f2bf(q0.x), f2bf(q0.y), f2bf(q0.z), f2bf(q0.w)};
      *(ushort4*)&ldsA[cur ^ 1][tid * 8 + 4] = ushort4{f2bf(q1.x), f2bf(q1.y), f2bf(q1.z), f2bf(q1.w)};
    }
    __syncthreads();   // next buf ready for all; cur's reads complete before overwrite
    cur ^= 1;
  }

#pragma unroll
  for (int j = 0; j < 4; j++) {
    int col = n0 + wn * 64 + j * 16 + l16;
    float bv = bias[col];
#pragma unroll
    for (int i = 0; i < 4; i++) {
      int row0 = m0 + wm * 64 + i * 16 + quad * 4;  // 4 consecutive rows
      if (STORE_T) {
        int nseg = row0 >> 8, tt0 = row0 & 255;
        ushort4 o;
        float v0 = acc[i][j][0] + bv, v1 = acc[i][j][1] + bv;
        float v2 = acc[i][j][2] + bv, v3 = acc[i][j][3] + bv;
        if (RELU) {
          v0 = fmaxf(v0, 0.f); v1 = fmaxf(v1, 0.f);
          v2 = fmaxf(v2, 0.f); v3 = fmaxf(v3, 0.f);
        }
        o.x = f2bf(v0); o.y = f2bf(v1); o.z = f2bf(v2); o.w = f2bf(v3);
        *(ushort4*)&out[(size_t)nseg * 65536 + (size_t)(col >> 6) * 16384 +
                        (col & 63) * 256 + tt0] = o;
      } else {
#pragma unroll
        for (int r = 0; r < 4; r++) {
          float v = acc[i][j][r] + bv;
          if (RELU) v = fmaxf(v, 0.f);
          out[(size_t)(row0 + r) * Nld + col] = f2bf(v);
        }
      }
    }
  }
}

// ---------------- K2: attention (in-place on xac) ----------------
// Wt (128 KB) is L2-resident: read A-fragments DIRECTLY from global (each block
// reads Wt exactly once, zero redundancy) -> no ldsW, no per-stage barriers.
// LDS 50->34 KB => 4 blocks/CU.
__global__ __launch_bounds__(256, 4) void k_attn(
    u16* xac,
    const u16* __restrict__ Wt,       // attn_w^T: [t'][t] 256x256
    const float* __restrict__ attn_b) {
  __shared__ u16 ldsC[16384];         // conv resident [tchunk 32][f 64][8]
  __shared__ float redmax[4][64];
  __shared__ float redsum[4][64];
  const int tid  = threadIdx.x;
  const int w    = tid >> 6;
  const int lane = tid & 63;
  const int quad = lane >> 4;
  const int l16  = lane & 15;
  const int seg = blockIdx.x;
  const int c4  = blockIdx.y;
  u16* reg = xac + (size_t)seg * 65536 + (size_t)c4 * 16384;

  {
    const int f = tid & 63, g = tid >> 6;
#pragma unroll
    for (int u = 0; u < 8; u++) {
      int tch = g * 8 + u;
      *(bf16x8*)&ldsC[(tch * 64 + f) * 8] =
          *(const bf16x8*)(reg + (size_t)f * 256 + tch * 8);
    }
  }
  __syncthreads();   // ldsC visible to all waves

  f32x4 acc[4][4];
#pragma unroll
  for (int i = 0; i < 4; i++)
#pragma unroll
    for (int j = 0; j < 4; j++) acc[i][j] = f32x4{0.f, 0.f, 0.f, 0.f};

#pragma unroll
  for (int s = 0; s < 8; s++) {
    int k0 = s * 32;
    bf16x8 a[4], b[4];
#pragma unroll
    for (int i = 0; i < 4; i++)
      a[i] = *(const bf16x8*)(Wt + (size_t)(w * 64 + i * 16 + l16) * 256 + k0 + quad * 8);
#pragma unroll
    for (int j = 0; j < 4; j++)
      b[j] = *(const bf16x8*)&ldsC[((s * 4 + quad) * 64 + j * 16 + l16) * 8];
#pragma unroll
    for (int i = 0; i < 4; i++)
#pragma unroll
      for (int j = 0; j < 4; j++)
        acc[i][j] = __builtin_amdgcn_mfma_f32_16x16x32_bf16(a[i], b[j], acc[i][j], 0, 0, 0);
  }

#pragma unroll
  for (int i = 0; i < 4; i++)
#pragma unroll
    for (int r = 0; r < 4; r++) {
      float ab = attn_b[w * 64 + i * 16 + quad * 4 + r];
#pragma unroll
      for (int j = 0; j < 4; j++) acc[i][j][r] += ab;
    }

  float lmax[4];
#pragma unroll
  for (int j = 0; j < 4; j++) {
    float m = -1e30f;
#pragma unroll
    for (int i = 0; i < 4; i++)
#pragma unroll
      for (int r = 0; r < 4; r++) m = fmaxf(m, acc[i][j][r]);
    m = fmaxf(m, __shfl_xor(m, 16));
    m = fmaxf(m, __shfl_xor(m, 32));
    lmax[j] = m;
  }
  if (quad == 0) {
#pragma unroll
    for (int j = 0; j < 4; j++) redmax[w][j * 16 + l16] = lmax[j];
  }
  __syncthreads();
  float gmax[4];
#pragma unroll
  for (int j = 0; j < 4; j++) {
    int c = j * 16 + l16;
    gmax[j] = fmaxf(fmaxf(redmax[0][c], redmax[1][c]), fmaxf(redmax[2][c], redmax[3][c]));
  }
  float lsum[4];
#pragma unroll
  for (int j = 0; j < 4; j++) {
    float sacc = 0.f;
#pragma unroll
    for (int i = 0; i < 4; i++)
#pragma unroll
      for (int r = 0; r < 4; r++) {
        float e = __expf(acc[i][j][r] - gmax[j]);
        acc[i][j][r] = e;
        sacc += e;
      }
    sacc += __shfl_xor(sacc, 16);
    sacc += __shfl_xor(sacc, 32);
    lsum[j] = sacc;
  }
  if (quad == 0) {
#pragma unroll
    for (int j = 0; j < 4; j++) redsum[w][j * 16 + l16] = lsum[j];
  }
  __syncthreads();
  float rinv[4];
#pragma unroll
  for (int j = 0; j < 4; j++) {
    int c = j * 16 + l16;
    rinv[j] = 1.0f / (redsum[0][c] + redsum[1][c] + redsum[2][c] + redsum[3][c]);
  }

#pragma unroll
  for (int i = 0; i < 4; i++) {
#pragma unroll
    for (int r = 0; r < 4; r++) {
      int tp = w * 64 + i * 16 + quad * 4 + r;
#pragma unroll
      for (int j = 0; j < 4; j++) {
        int fl = j * 16 + l16;
        float cv = bf2f(ldsC[((tp >> 3) * 64 + fl) * 8 + (tp & 7)]);
        float xa = acc[i][j][r] * rinv[j] * cv;
        reg[(size_t)tp * 64 + fl] = f2bf(xa);
      }
    }
  }
}

// ---------------- K4c: GRU scan over one time chunk (TC steps) ----------------
// 64 blocks x 512 thr (8 waves), 16 segs/block. Ut fragments: 4 of 6 sets
// register-resident (g0 z,r,h + g1 h = 128 VGPR), 2 sets (g1 z,r) staged in
// LDS once per launch. Per-step global traffic: gates only (h-independent).
// h carried between chunks via hio (= d_out) in fp32.
__global__ __launch_bounds__(512, 2) void k_scanc(
    const u16* __restrict__ gc,   // gates chunk [NSEG*TC][768] (x@W + bi)
    const u16* __restrict__ Ut,   // gru_u^T [768][256]
    const float* __restrict__ br, // gru_b[1]: [768]
    float* __restrict__ hio,      // [NSEG][256] fp32 (d_out)
    int init) {
  __shared__ u16 uls[65536];      // [w 8][set 2][s 8][lane 64][8]  = 128 KB
  __shared__ u16 hb[16 * 264];    // bf16 h, row stride 264
  const int tid  = threadIdx.x;
  const int w    = tid >> 6;
  const int lane = tid & 63;
  const int quad = lane >> 4;
  const int l16  = lane & 15;
  const int n0 = blockIdx.x * 16;
  const int cg[2] = {w, 8 + w};   // two col-groups per wave

  // stage g1 z,r Ut fragments into LDS (once)
#pragma unroll
  for (int j = 0; j < 2; j++)
#pragma unroll
    for (int s = 0; s < 8; s++)
      *(bf16x8*)&uls[w * 8192 + (j * 8 + s) * 512 + lane * 8] =
          *(const bf16x8*)(Ut + (size_t)(j * 256 + cg[1] * 16 + l16) * 256 + s * 32 + quad * 8);

  // register-resident Ut fragments: g0 all gates, g1 gate h
  bf16x8 ur0[3][8], urh1[8];
#pragma unroll
  for (int g = 0; g < 3; g++)
#pragma unroll
    for (int s = 0; s < 8; s++)
      ur0[g][s] = *(const bf16x8*)(Ut + (size_t)(g * 256 + cg[0] * 16 + l16) * 256 + s * 32 + quad * 8);
#pragma unroll
  for (int s = 0; s < 8; s++)
    urh1[s] = *(const bf16x8*)(Ut + (size_t)(512 + cg[1] * 16 + l16) * 256 + s * 32 + quad * 8);

  // biases per (group, gate)
  float brZ[2], brR[2], brH[2];
#pragma unroll
  for (int grp = 0; grp < 2; grp++) {
    int c = cg[grp] * 16 + l16;
    brZ[grp] = br[c]; brR[grp] = br[256 + c]; brH[grp] = br[512 + c];
  }

  // h init: registers (this lane's 4 segs x 2 groups) + hb for all 16 segs
  float hreg[2][4];
#pragma unroll
  for (int grp = 0; grp < 2; grp++)
#pragma unroll
    for (int r = 0; r < 4; r++)
      hreg[grp][r] = init ? 0.f
                          : hio[(size_t)(n0 + quad * 4 + r) * 256 + cg[grp] * 16 + l16];
  {
    int sg = tid >> 5, c0 = (tid & 31) * 8;   // 16 segs x 256 cols / 512 thr
    if (init) {
      *(ushort4*)&hb[sg * 264 + c0]     = ushort4{0, 0, 0, 0};
      *(ushort4*)&hb[sg * 264 + c0 + 4] = ushort4{0, 0, 0, 0};
    } else {
      const float* hp = hio + (size_t)(n0 + sg) * 256 + c0;
      float4 h0 = *(const float4*)(hp), h1 = *(const float4*)(hp + 4);
      *(ushort4*)&hb[sg * 264 + c0]     = ushort4{f2bf(h0.x), f2bf(h0.y), f2bf(h0.z), f2bf(h0.w)};
      *(ushort4*)&hb[sg * 264 + c0 + 4] = ushort4{f2bf(h1.x), f2bf(h1.y), f2bf(h1.z), f2bf(h1.w)};
    }
  }
  // gates row bases for this lane's 4 segs
  const u16* gseg[4];
#pragma unroll
  for (int r = 0; r < 4; r++)
    gseg[r] = gc + (size_t)(n0 + quad * 4 + r) * TC * 768;
  __syncthreads();

  for (int tt = 0; tt < TC; tt++) {
    // prefetch gates[tt] (h-independent)
    float gg[2][3][4];
#pragma unroll
    for (int grp = 0; grp < 2; grp++)
#pragma unroll
      for (int g = 0; g < 3; g++)
#pragma unroll
        for (int r = 0; r < 4; r++)
          gg[grp][g][r] = bf2f(gseg[r][tt * 768 + g * 256 + cg[grp] * 16 + l16]);

    f32x4 acc[2][3];
#pragma unroll
    for (int grp = 0; grp < 2; grp++)
#pragma unroll
      for (int g = 0; g < 3; g++) acc[grp][g] = f32x4{0.f, 0.f, 0.f, 0.f};

#pragma unroll
    for (int s = 0; s < 8; s++) {
      bf16x8 ah = *(const bf16x8*)&hb[l16 * 264 + s * 32 + quad * 8];
#pragma unroll
      for (int g = 0; g < 3; g++)
        acc[0][g] = __builtin_amdgcn_mfma_f32_16x16x32_bf16(ah, ur0[g][s], acc[0][g], 0, 0, 0);
      bf16x8 uz = *(const bf16x8*)&uls[w * 8192 + s * 512 + lane * 8];
      bf16x8 urr = *(const bf16x8*)&uls[w * 8192 + (8 + s) * 512 + lane * 8];
      acc[1][0] = __builtin_amdgcn_mfma_f32_16x16x32_bf16(ah, uz,      acc[1][0], 0, 0, 0);
      acc[1][1] = __builtin_amdgcn_mfma_f32_16x16x32_bf16(ah, urr,     acc[1][1], 0, 0, 0);
      acc[1][2] = __builtin_amdgcn_mfma_f32_16x16x32_bf16(ah, urh1[s], acc[1][2], 0, 0, 0);
    }
    __syncthreads();   // all hb reads complete before overwrite

#pragma unroll
    for (int grp = 0; grp < 2; grp++)
#pragma unroll
      for (int r = 0; r < 4; r++) {
        float z  = sigm(acc[grp][0][r] + gg[grp][0][r] + brZ[grp]);
        float rg = sigm(acc[grp][1][r] + gg[grp][1][r] + brR[grp]);
        float hh = fmaxf(gg[grp][2][r] + rg * (acc[grp][2][r] + brH[grp]), 0.f);
        float hn = z * hreg[grp][r] + (1.0f - z) * hh;
        hreg[grp][r] = hn;
        hb[(quad * 4 + r) * 264 + cg[grp] * 16 + l16] = f2bf(hn);
      }
    __syncthreads();   // writes visible before next step's reads
  }

#pragma unroll
  for (int grp = 0; grp < 2; grp++)
#pragma unroll
    for (int r = 0; r < 4; r++)
      hio[(size_t)(n0 + quad * 4 + r) * 256 + cg[grp] * 16 + l16] = hreg[grp][r];
}

// ---------------- host ----------------
extern "C" void kernel_launch(void* const* d_in, const int* in_sizes, int n_in,
                              void* d_out, int out_size, void* d_ws, size_t ws_size,
                              hipStream_t stream) {
  (void)in_sizes; (void)n_in; (void)out_size;
  const float* x      = (const float*)d_in[0];
  const float* conv_w = (const float*)d_in[1];
  const float* conv_b = (const float*)d_in[2];
  const float* attn_w = (const float*)d_in[3];
  const float* attn_b = (const float*)d_in[4];
  const float* gru_w  = (const float*)d_in[5];
  const float* gru_u  = (const float*)d_in[6];
  const float* gru_b  = (const float*)d_in[7];

  // scratch layout: 185,532,416 B total (known-safe: < 202,309,696 proven)
  const size_t NEEDED = 185532416;
  if (ws_size < NEEDED) return;
  char* ws = (char*)d_ws;
  u16* xac     = (u16*)(ws);                  // 134217728 B: convT then x_att (chunked, in-place)
  u16* gatesC  = (u16*)(ws + 134217728);      //  50331648 B: gates for one 32-step chunk
  u16* conv_wT = (u16*)(ws + 184549376);      //     65536 B [f][c]
  u16* attn_wT = (u16*)(ws + 184614912);      //    131072 B [t'][t]
  u16* gru_wT  = (u16*)(ws + 184745984);      //    393216 B [j][f]
  u16* gru_uT  = (u16*)(ws + 185139200);      //    393216 B [j][k]

  hipLaunchKernelGGL(k_transp, dim3(128), dim3(256), 0, stream, conv_w, conv_wT, 128, 256);
  hipLaunchKernelGGL(k_transp, dim3(256), dim3(256), 0, stream, attn_w, attn_wT, 256, 256);
  hipLaunchKernelGGL(k_transp, dim3(768), dim3(256), 0, stream, gru_w, gru_wT, 256, 768);
  hipLaunchKernelGGL(k_transp, dim3(768), dim3(256), 0, stream, gru_u, gru_uT, 256, 768);

  // K1: conv = relu(x @ conv_w + b); full N=256 per block -> fp32 A read ONCE
  hipLaunchKernelGGL((k_gemm<true, true, 0>), dim3(2048, 1), dim3(512), 0, stream,
                     (const void*)x, conv_wT, conv_b, xac, 128, 0, 0);
  // K2: attention softmax + multiply, in place on xac
  hipLaunchKernelGGL(k_attn, dim3(1024, 4), dim3(256), 0, stream,
                     xac, attn_wT, attn_b);
  // K3c/K4c: 8 time chunks of (gates GEMM -> 32-step scan); h lives in d_out
  // gates grid (256,3): 256 % 8 == 0 keeps all 3 n-passes of an m-tile on the
  // same XCD; A per XCD = 2 MB < 4 MB L2 -> A effectively fetched once.
  for (int c = 0; c < 8; c++) {
    hipLaunchKernelGGL((k_gemm<false, false, 1>), dim3(256, 3), dim3(512), 0, stream,
                       (const void*)xac, gru_wT, gru_b, gatesC, 256, 768, c * TC);
    hipLaunchKernelGGL(k_scanc, dim3(64), dim3(512), 0, stream,
                       gatesC, gru_uT, gru_b + 768, (float*)d_out, c == 0 ? 1 : 0);
  }
}

// Round 3
// 1227.424 us; speedup vs baseline: 1.0281x; 1.0097x over previous
//
#include <hip/hip_runtime.h>
#include <stdint.h>

typedef unsigned short u16;
typedef __attribute__((ext_vector_type(8))) __bf16 bf16x8;
typedef __attribute__((ext_vector_type(4))) float f32x4;

#define TTS 256
#define NSEG 1024
#define TC 32            // time-chunk for gates

__device__ __forceinline__ u16 f2bf(float f) {
  union { float f; uint32_t u; } v; v.f = f;
  uint32_t r = v.u + 0x7fffu + ((v.u >> 16) & 1u);
  return (u16)(r >> 16);
}
__device__ __forceinline__ float bf2f(u16 h) {
  union { uint32_t u; float f; } v; v.u = ((uint32_t)h) << 16;
  return v.f;
}
__device__ __forceinline__ float sigm(float x) {
  return __builtin_amdgcn_rcpf(1.0f + __expf(-x));
}
// async global->LDS, 16B per lane; LDS dest must be wave-uniform base + lane*16
__device__ __forceinline__ void gl16(const void* g, void* l) {
  __builtin_amdgcn_global_load_lds(
      (const __attribute__((address_space(1))) unsigned int*)g,
      (__attribute__((address_space(3))) unsigned int*)l, 16, 0, 0);
}

// ---------------- K0: transpose small weight, fp32 -> bf16 ----------------
__global__ void k_transp(const float* __restrict__ in, u16* __restrict__ out, int R, int C) {
  int i = blockIdx.x * blockDim.x + threadIdx.x;
  if (i < R * C) {
    int r = i / C, c = i % C;
    out[(size_t)c * R + r] = f2bf(in[i]);
  }
}

// ---------------- K1/K3c: bf16 MFMA GEMM, 128x256 tile, BK=32, 512 thr ----------------
// 2-phase double-buffered: stage tile k+1 (global_load_lds / reg-split for fp32)
// while MFMA'ing tile k; ONE barrier per K-step.
// AMODE 0: A fp32 row-major [M][K] (K1: x), load->convert->ds_write staging.
// AMODE 1: A bf16 chunked x_att [seg][k>>6][t][64], staged via global_load_lds.
// STORE_T: write chunked convT layout [seg][f>>6][f&63][t]. Else row-major [M][Nld].
template <bool RELU, bool STORE_T, int AMODE>
__global__ __launch_bounds__(512, 2) void k_gemm(
    const void* __restrict__ Av, const u16* __restrict__ Bt,
    const float* __restrict__ bias, u16* __restrict__ out, int K, int Nld, int t0) {
  __shared__ __attribute__((aligned(16))) u16 ldsA[2][4096];   // [c 4][row 128][8]
  __shared__ __attribute__((aligned(16))) u16 ldsB[2][8192];   // [c 4][row 256][8]
  const int tid  = threadIdx.x;
  const int w    = tid >> 6;
  const int lane = tid & 63;
  const int quad = lane >> 4;
  const int l16  = lane & 15;
  const int m0 = blockIdx.x * 128;
  const int n0 = blockIdx.y * 256;
  const int wm = w >> 2, wn = w & 3;          // 2x4 wave grid, wave tile 64x64
  const int arow = tid & 127, ac = tid >> 7;  // A staging: (row, k-subchunk)
  const float* Af = (const float*)Av;
  const u16*   Ax = (const u16*)Av;

  f32x4 acc[4][4];
#pragma unroll
  for (int i = 0; i < 4; i++)
#pragma unroll
    for (int j = 0; j < 4; j++) acc[i][j] = f32x4{0.f, 0.f, 0.f, 0.f};

  // ---- prologue: stage k0=0 into buffer 0 ----
  float4 p0, p1;
  if (AMODE == 0) {
    const float* p = Af + (size_t)(m0 + arow) * K + ac * 8;
    p0 = *(const float4*)p;
    p1 = *(const float4*)(p + 4);
  } else {
    int r = m0 + arow, kk = ac * 8;
    gl16(Ax + (size_t)(r >> 5) * 65536 + (size_t)(kk >> 6) * 16384 +
             (t0 + (r & 31)) * 64 + (kk & 63),
         &ldsA[0][tid * 8]);
  }
#pragma unroll
  for (int i = 0; i < 2; i++) {
    int idx = i * 512 + tid, brow = idx & 255, bc = idx >> 8;
    gl16(Bt + (size_t)(n0 + brow) * K + bc * 8, &ldsB[0][idx * 8]);
  }
  if (AMODE == 0) {
    *(ushort4*)&ldsA[0][tid * 8]     = ushort4{f2bf(p0.x), f2bf(p0.y), f2bf(p0.z), f2bf(p0.w)};
    *(ushort4*)&ldsA[0][tid * 8 + 4] = ushort4{f2bf(p1.x), f2bf(p1.y), f2bf(p1.z), f2bf(p1.w)};
  }
  __syncthreads();   // vmcnt drained (gl16 landed) + ds_writes visible

  int cur = 0;
  for (int k0 = 0; k0 < K; k0 += 32) {
    const int kn = k0 + 32;
    const bool more = kn < K;
    // ---- issue next-tile staging into buf cur^1 (before compute) ----
    float4 q0, q1;
    if (more) {
      if (AMODE == 0) {
        const float* p = Af + (size_t)(m0 + arow) * K + kn + ac * 8;
        q0 = *(const float4*)p;
        q1 = *(const float4*)(p + 4);
      } else {
        int r = m0 + arow, kk = kn + ac * 8;
        gl16(Ax + (size_t)(r >> 5) * 65536 + (size_t)(kk >> 6) * 16384 +
                 (t0 + (r & 31)) * 64 + (kk & 63),
             &ldsA[cur ^ 1][tid * 8]);
      }
#pragma unroll
      for (int i = 0; i < 2; i++) {
        int idx = i * 512 + tid, brow = idx & 255, bc = idx >> 8;
        gl16(Bt + (size_t)(n0 + brow) * K + kn + bc * 8, &ldsB[cur ^ 1][idx * 8]);
      }
    }
    // ---- compute on buf cur ----
    bf16x8 a[4], b[4];
#pragma unroll
    for (int i = 0; i < 4; i++)
      a[i] = *(const bf16x8*)&ldsA[cur][(quad * 128 + wm * 64 + i * 16 + l16) * 8];
#pragma unroll
    for (int j = 0; j < 4; j++)
      b[j] = *(const bf16x8*)&ldsB[cur][(quad * 256 + wn * 64 + j * 16 + l16) * 8];
#pragma unroll
    for (int i = 0; i < 4; i++)
#pragma unroll
      for (int j = 0; j < 4; j++)
        acc[i][j] = __builtin_amdgcn_mfma_f32_16x16x32_bf16(a[i], b[j], acc[i][j], 0, 0, 0);
    // fp32-A path: convert+write next tile after compute (loads have landed by now)
    if (AMODE == 0 && more) {
      *(ushort4*)&ldsA[cur ^ 1][tid * 8]     = ushort4{f2bf(q0.x), f2bf(q0.y), f2bf(q0.z), f2bf(q0.w)};
      *(ushort4*)&ldsA[cur ^ 1][tid * 8 + 4] = ushort4{f2bf(q1.x), f2bf(q1.y), f2bf(q1.z), f2bf(q1.w)};
    }
    __syncthreads();   // next buf ready for all; cur's reads complete before overwrite
    cur ^= 1;
  }

#pragma unroll
  for (int j = 0; j < 4; j++) {
    int col = n0 + wn * 64 + j * 16 + l16;
    float bv = bias[col];
#pragma unroll
    for (int i = 0; i < 4; i++) {
      int row0 = m0 + wm * 64 + i * 16 + quad * 4;  // 4 consecutive rows
      if (STORE_T) {
        int nseg = row0 >> 8, tt0 = row0 & 255;
        ushort4 o;
        float v0 = acc[i][j][0] + bv, v1 = acc[i][j][1] + bv;
        float v2 = acc[i][j][2] + bv, v3 = acc[i][j][3] + bv;
        if (RELU) {
          v0 = fmaxf(v0, 0.f); v1 = fmaxf(v1, 0.f);
          v2 = fmaxf(v2, 0.f); v3 = fmaxf(v3, 0.f);
        }
        o.x = f2bf(v0); o.y = f2bf(v1); o.z = f2bf(v2); o.w = f2bf(v3);
        *(ushort4*)&out[(size_t)nseg * 65536 + (size_t)(col >> 6) * 16384 +
                        (col & 63) * 256 + tt0] = o;
      } else {
#pragma unroll
        for (int r = 0; r < 4; r++) {
          float v = acc[i][j][r] + bv;
          if (RELU) v = fmaxf(v, 0.f);
          out[(size_t)(row0 + r) * Nld + col] = f2bf(v);
        }
      }
    }
  }
}

// ---------------- K2: attention (in-place on xac) ----------------
// Wt (128 KB) is L2-resident: read A-fragments DIRECTLY from global (each block
// reads Wt exactly once, zero redundancy) -> no ldsW, no per-stage barriers.
__global__ __launch_bounds__(256, 4) void k_attn(
    u16* xac,
    const u16* __restrict__ Wt,       // attn_w^T: [t'][t] 256x256
    const float* __restrict__ attn_b) {
  __shared__ u16 ldsC[16384];         // conv resident [tchunk 32][f 64][8]
  __shared__ float redmax[4][64];
  __shared__ float redsum[4][64];
  const int tid  = threadIdx.x;
  const int w    = tid >> 6;
  const int lane = tid & 63;
  const int quad = lane >> 4;
  const int l16  = lane & 15;
  const int seg = blockIdx.x;
  const int c4  = blockIdx.y;
  u16* reg = xac + (size_t)seg * 65536 + (size_t)c4 * 16384;

  {
    const int f = tid & 63, g = tid >> 6;
#pragma unroll
    for (int u = 0; u < 8; u++) {
      int tch = g * 8 + u;
      *(bf16x8*)&ldsC[(tch * 64 + f) * 8] =
          *(const bf16x8*)(reg + (size_t)f * 256 + tch * 8);
    }
  }
  __syncthreads();   // ldsC visible to all waves

  f32x4 acc[4][4];
#pragma unroll
  for (int i = 0; i < 4; i++)
#pragma unroll
    for (int j = 0; j < 4; j++) acc[i][j] = f32x4{0.f, 0.f, 0.f, 0.f};

#pragma unroll
  for (int s = 0; s < 8; s++) {
    int k0 = s * 32;
    bf16x8 a[4], b[4];
#pragma unroll
    for (int i = 0; i < 4; i++)
      a[i] = *(const bf16x8*)(Wt + (size_t)(w * 64 + i * 16 + l16) * 256 + k0 + quad * 8);
#pragma unroll
    for (int j = 0; j < 4; j++)
      b[j] = *(const bf16x8*)&ldsC[((s * 4 + quad) * 64 + j * 16 + l16) * 8];
#pragma unroll
    for (int i = 0; i < 4; i++)
#pragma unroll
      for (int j = 0; j < 4; j++)
        acc[i][j] = __builtin_amdgcn_mfma_f32_16x16x32_bf16(a[i], b[j], acc[i][j], 0, 0, 0);
  }

#pragma unroll
  for (int i = 0; i < 4; i++)
#pragma unroll
    for (int r = 0; r < 4; r++) {
      float ab = attn_b[w * 64 + i * 16 + quad * 4 + r];
#pragma unroll
      for (int j = 0; j < 4; j++) acc[i][j][r] += ab;
    }

  float lmax[4];
#pragma unroll
  for (int j = 0; j < 4; j++) {
    float m = -1e30f;
#pragma unroll
    for (int i = 0; i < 4; i++)
#pragma unroll
      for (int r = 0; r < 4; r++) m = fmaxf(m, acc[i][j][r]);
    m = fmaxf(m, __shfl_xor(m, 16));
    m = fmaxf(m, __shfl_xor(m, 32));
    lmax[j] = m;
  }
  if (quad == 0) {
#pragma unroll
    for (int j = 0; j < 4; j++) redmax[w][j * 16 + l16] = lmax[j];
  }
  __syncthreads();
  float gmax[4];
#pragma unroll
  for (int j = 0; j < 4; j++) {
    int c = j * 16 + l16;
    gmax[j] = fmaxf(fmaxf(redmax[0][c], redmax[1][c]), fmaxf(redmax[2][c], redmax[3][c]));
  }
  float lsum[4];
#pragma unroll
  for (int j = 0; j < 4; j++) {
    float sacc = 0.f;
#pragma unroll
    for (int i = 0; i < 4; i++)
#pragma unroll
      for (int r = 0; r < 4; r++) {
        float e = __expf(acc[i][j][r] - gmax[j]);
        acc[i][j][r] = e;
        sacc += e;
      }
    sacc += __shfl_xor(sacc, 16);
    sacc += __shfl_xor(sacc, 32);
    lsum[j] = sacc;
  }
  if (quad == 0) {
#pragma unroll
    for (int j = 0; j < 4; j++) redsum[w][j * 16 + l16] = lsum[j];
  }
  __syncthreads();
  float rinv[4];
#pragma unroll
  for (int j = 0; j < 4; j++) {
    int c = j * 16 + l16;
    rinv[j] = 1.0f / (redsum[0][c] + redsum[1][c] + redsum[2][c] + redsum[3][c]);
  }

#pragma unroll
  for (int i = 0; i < 4; i++) {
#pragma unroll
    for (int r = 0; r < 4; r++) {
      int tp = w * 64 + i * 16 + quad * 4 + r;
#pragma unroll
      for (int j = 0; j < 4; j++) {
        int fl = j * 16 + l16;
        float cv = bf2f(ldsC[((tp >> 3) * 64 + fl) * 8 + (tp & 7)]);
        float xa = acc[i][j][r] * rinv[j] * cv;
        reg[(size_t)tp * 64 + fl] = f2bf(xa);
      }
    }
  }
}

// ---------------- K4c: GRU scan over one time chunk (TC steps) ----------------
// v2: (a) double-buffered h in LDS -> ONE barrier per step (was 2);
//     (b) gate loads software-pipelined one step ahead (raw u16 in regs,
//         bf2f deferred to use) so the ~900-cyc HBM latency hides under the
//         MFMA block of the previous step. Static buffer indexing via 2-step
//         unrolled loop (no runtime-indexed reg arrays).
__global__ __launch_bounds__(512, 2) void k_scanc(
    const u16* __restrict__ gc,   // gates chunk [NSEG*TC][768] (x@W + bi)
    const u16* __restrict__ Ut,   // gru_u^T [768][256]
    const float* __restrict__ br, // gru_b[1]: [768]
    float* __restrict__ hio,      // [NSEG][256] fp32 (d_out)
    int init) {
  __shared__ u16 uls[65536];      // [w 8][set 2][s 8][lane 64][8]  = 128 KB
  __shared__ u16 hb[2][16 * 264]; // bf16 h, double-buffered, row stride 264
  const int tid  = threadIdx.x;
  const int w    = tid >> 6;
  const int lane = tid & 63;
  const int quad = lane >> 4;
  const int l16  = lane & 15;
  const int n0 = blockIdx.x * 16;
  const int cg[2] = {w, 8 + w};   // two col-groups per wave

  // stage g1 z,r Ut fragments into LDS (once)
#pragma unroll
  for (int j = 0; j < 2; j++)
#pragma unroll
    for (int s = 0; s < 8; s++)
      *(bf16x8*)&uls[w * 8192 + (j * 8 + s) * 512 + lane * 8] =
          *(const bf16x8*)(Ut + (size_t)(j * 256 + cg[1] * 16 + l16) * 256 + s * 32 + quad * 8);

  // register-resident Ut fragments: g0 all gates, g1 gate h
  bf16x8 ur0[3][8], urh1[8];
#pragma unroll
  for (int g = 0; g < 3; g++)
#pragma unroll
    for (int s = 0; s < 8; s++)
      ur0[g][s] = *(const bf16x8*)(Ut + (size_t)(g * 256 + cg[0] * 16 + l16) * 256 + s * 32 + quad * 8);
#pragma unroll
  for (int s = 0; s < 8; s++)
    urh1[s] = *(const bf16x8*)(Ut + (size_t)(512 + cg[1] * 16 + l16) * 256 + s * 32 + quad * 8);

  // biases per (group, gate)
  float brZ[2], brR[2], brH[2];
#pragma unroll
  for (int grp = 0; grp < 2; grp++) {
    int c = cg[grp] * 16 + l16;
    brZ[grp] = br[c]; brR[grp] = br[256 + c]; brH[grp] = br[512 + c];
  }

  // h init: registers (this lane's 4 segs x 2 groups) + hb[0] for all 16 segs
  float hreg[2][4];
#pragma unroll
  for (int grp = 0; grp < 2; grp++)
#pragma unroll
    for (int r = 0; r < 4; r++)
      hreg[grp][r] = init ? 0.f
                          : hio[(size_t)(n0 + quad * 4 + r) * 256 + cg[grp] * 16 + l16];
  {
    int sg = tid >> 5, c0 = (tid & 31) * 8;   // 16 segs x 256 cols / 512 thr
    if (init) {
      *(ushort4*)&hb[0][sg * 264 + c0]     = ushort4{0, 0, 0, 0};
      *(ushort4*)&hb[0][sg * 264 + c0 + 4] = ushort4{0, 0, 0, 0};
    } else {
      const float* hp = hio + (size_t)(n0 + sg) * 256 + c0;
      float4 h0 = *(const float4*)(hp), h1 = *(const float4*)(hp + 4);
      *(ushort4*)&hb[0][sg * 264 + c0]     = ushort4{f2bf(h0.x), f2bf(h0.y), f2bf(h0.z), f2bf(h0.w)};
      *(ushort4*)&hb[0][sg * 264 + c0 + 4] = ushort4{f2bf(h1.x), f2bf(h1.y), f2bf(h1.z), f2bf(h1.w)};
    }
  }
  // gates row bases for this lane's 4 segs
  const u16* gseg[4];
#pragma unroll
  for (int r = 0; r < 4; r++)
    gseg[r] = gc + (size_t)(n0 + quad * 4 + r) * TC * 768;
  __syncthreads();

  // gate prefetch buffers (raw u16; bf2f at use)
  u16 gA[2][3][4], gB[2][3][4];

  auto load_g = [&](int tt, u16 (&gr)[2][3][4]) {
#pragma unroll
    for (int grp = 0; grp < 2; grp++)
#pragma unroll
      for (int g = 0; g < 3; g++)
#pragma unroll
        for (int r = 0; r < 4; r++)
          gr[grp][g][r] = gseg[r][tt * 768 + g * 256 + cg[grp] * 16 + l16];
  };

  // one scan step: reads hb[CUR], writes hb[CUR^1]; issues next-step gate loads
  // BEFORE the MFMA block so HBM latency hides under it. ONE barrier.
  auto step = [&](int tt, const u16 (&gcur)[2][3][4], u16 (&gnext)[2][3][4],
                  int CUR) {
    if (tt + 1 < TC) load_g(tt + 1, gnext);

    f32x4 acc[2][3];
#pragma unroll
    for (int grp = 0; grp < 2; grp++)
#pragma unroll
      for (int g = 0; g < 3; g++) acc[grp][g] = f32x4{0.f, 0.f, 0.f, 0.f};

#pragma unroll
    for (int s = 0; s < 8; s++) {
      bf16x8 ah = *(const bf16x8*)&hb[CUR][l16 * 264 + s * 32 + quad * 8];
#pragma unroll
      for (int g = 0; g < 3; g++)
        acc[0][g] = __builtin_amdgcn_mfma_f32_16x16x32_bf16(ah, ur0[g][s], acc[0][g], 0, 0, 0);
      bf16x8 uz  = *(const bf16x8*)&uls[w * 8192 + s * 512 + lane * 8];
      bf16x8 urr = *(const bf16x8*)&uls[w * 8192 + (8 + s) * 512 + lane * 8];
      acc[1][0] = __builtin_amdgcn_mfma_f32_16x16x32_bf16(ah, uz,      acc[1][0], 0, 0, 0);
      acc[1][1] = __builtin_amdgcn_mfma_f32_16x16x32_bf16(ah, urr,     acc[1][1], 0, 0, 0);
      acc[1][2] = __builtin_amdgcn_mfma_f32_16x16x32_bf16(ah, urh1[s], acc[1][2], 0, 0, 0);
    }

#pragma unroll
    for (int grp = 0; grp < 2; grp++)
#pragma unroll
      for (int r = 0; r < 4; r++) {
        float z  = sigm(acc[grp][0][r] + bf2f(gcur[grp][0][r]) + brZ[grp]);
        float rg = sigm(acc[grp][1][r] + bf2f(gcur[grp][1][r]) + brR[grp]);
        float hh = fmaxf(bf2f(gcur[grp][2][r]) + rg * (acc[grp][2][r] + brH[grp]), 0.f);
        float hn = z * hreg[grp][r] + (1.0f - z) * hh;
        hreg[grp][r] = hn;
        hb[CUR ^ 1][(quad * 4 + r) * 264 + cg[grp] * 16 + l16] = f2bf(hn);
      }
    __syncthreads();   // hb[CUR^1] writes visible; all hb[CUR] reads retired
  };

  load_g(0, gA);
  for (int t2 = 0; t2 < TC; t2 += 2) {
    step(t2,     gA, gB, 0);
    step(t2 + 1, gB, gA, 1);
  }

#pragma unroll
  for (int grp = 0; grp < 2; grp++)
#pragma unroll
    for (int r = 0; r < 4; r++)
      hio[(size_t)(n0 + quad * 4 + r) * 256 + cg[grp] * 16 + l16] = hreg[grp][r];
}

// ---------------- host ----------------
extern "C" void kernel_launch(void* const* d_in, const int* in_sizes, int n_in,
                              void* d_out, int out_size, void* d_ws, size_t ws_size,
                              hipStream_t stream) {
  (void)in_sizes; (void)n_in; (void)out_size;
  const float* x      = (const float*)d_in[0];
  const float* conv_w = (const float*)d_in[1];
  const float* conv_b = (const float*)d_in[2];
  const float* attn_w = (const float*)d_in[3];
  const float* attn_b = (const float*)d_in[4];
  const float* gru_w  = (const float*)d_in[5];
  const float* gru_u  = (const float*)d_in[6];
  const float* gru_b  = (const float*)d_in[7];

  // scratch layout: 185,532,416 B total (known-safe: < 202,309,696 proven)
  const size_t NEEDED = 185532416;
  if (ws_size < NEEDED) return;
  char* ws = (char*)d_ws;
  u16* xac     = (u16*)(ws);                  // 134217728 B: convT then x_att (chunked, in-place)
  u16* gatesC  = (u16*)(ws + 134217728);      //  50331648 B: gates for one 32-step chunk
  u16* conv_wT = (u16*)(ws + 184549376);      //     65536 B [f][c]
  u16* attn_wT = (u16*)(ws + 184614912);      //    131072 B [t'][t]
  u16* gru_wT  = (u16*)(ws + 184745984);      //    393216 B [j][f]
  u16* gru_uT  = (u16*)(ws + 185139200);      //    393216 B [j][k]

  hipLaunchKernelGGL(k_transp, dim3(128), dim3(256), 0, stream, conv_w, conv_wT, 128, 256);
  hipLaunchKernelGGL(k_transp, dim3(256), dim3(256), 0, stream, attn_w, attn_wT, 256, 256);
  hipLaunchKernelGGL(k_transp, dim3(768), dim3(256), 0, stream, gru_w, gru_wT, 256, 768);
  hipLaunchKernelGGL(k_transp, dim3(768), dim3(256), 0, stream, gru_u, gru_uT, 256, 768);

  // K1: conv = relu(x @ conv_w + b); full N=256 per block -> fp32 A read ONCE
  hipLaunchKernelGGL((k_gemm<true, true, 0>), dim3(2048, 1), dim3(512), 0, stream,
                     (const void*)x, conv_wT, conv_b, xac, 128, 0, 0);
  // K2: attention softmax + multiply, in place on xac
  hipLaunchKernelGGL(k_attn, dim3(1024, 4), dim3(256), 0, stream,
                     xac, attn_wT, attn_b);
  // K3c/K4c: 8 time chunks of (gates GEMM -> 32-step scan); h lives in d_out
  for (int c = 0; c < 8; c++) {
    hipLaunchKernelGGL((k_gemm<false, false, 1>), dim3(256, 3), dim3(512), 0, stream,
                       (const void*)xac, gru_wT, gru_b, gatesC, 256, 768, c * TC);
    hipLaunchKernelGGL(k_scanc, dim3(64), dim3(512), 0, stream,
                       gatesC, gru_uT, gru_b + 768, (float*)d_out, c == 0 ? 1 : 0);
  }
}